// Round 12
// baseline (112.836 us; speedup 1.0000x reference)
//
#include <hip/hip_runtime.h>

// MultiModalFusion collapses analytically (exact, softmax shift-invariance):
//   attn = softmax_t(c_s * x_j[t]),  c_s = alpha*x_i[s] + gamma
//   out[b,n,i,s] = Ebar * mean_{j!=i} [ (sum_t e^{c x_jt} x_jt)/(sum_t e^{c x_jt}) ] + bvbar
//
// Round-10 postmortem: 2x waves did NOT help -> not latency-bound. Measured
// exp throughput ~7-8 lanes/cy/CU => v_exp_f32 (trans pipe) is the bottleneck.
// This version: dual-pipe exp. Half the weights via HW v_exp_f32, half via an
// inline degree-5 2^f polynomial (12 VALU ops, rel err ~3e-6) so the trans
// pipe and the VALU pipe run concurrently. Exact algorithm, 256-thr blocks
// (measured-best structure, round 5).

#if __has_builtin(__builtin_amdgcn_exp2f)
#define EXP2(v) __builtin_amdgcn_exp2f(v)
#else
#define EXP2(v) exp2f(v)
#endif

static __device__ __forceinline__ float hsum4(float4 v) { return (v.x + v.y) + (v.z + v.w); }

// VALU-pipe 2^z: round-to-int via magic, degree-5 Taylor on f in [-0.5,0.5],
// exponent insertion via int add on the float bits. |z| <= ~20 safe.
static __device__ __forceinline__ float exp2_poly(float z) {
    const float magic = 12582912.0f;              // 0x1.8p23
    float r  = z + magic;                         // RN to integer
    float nf = r - magic;
    float f  = z - nf;                            // f in [-0.5, 0.5]
    int   n  = __float_as_int(r) - 0x4B400000;    // integer part of z
    float p  = fmaf(0.0013333558f, f, 0.0096181291f);
    p = fmaf(p, f, 0.0555041087f);
    p = fmaf(p, f, 0.2402265070f);
    p = fmaf(p, f, 0.6931471806f);
    p = fmaf(p, f, 1.0f);                         // 2^f, rel err ~3e-6
    return __int_as_float(__float_as_int(p) + (n << 23));
}

// One wave: compute the 4 scalars into sc[0..3].
__global__ void mm_prep(const float* __restrict__ Wq, const float* __restrict__ bq,
                        const float* __restrict__ Wk, const float* __restrict__ bk,
                        const float* __restrict__ Wv, const float* __restrict__ bv,
                        float* __restrict__ sc) {
    const int k = threadIdx.x;  // 0..63
    const float4* wq4 = reinterpret_cast<const float4*>(Wq) + k * 32;
    const float4* wk4 = reinterpret_cast<const float4*>(Wk) + k * 32;
    const float4* wv4 = reinterpret_cast<const float4*>(Wv) + k * 32;
    float a = 0.f, c = 0.f, e = 0.f;
    #pragma unroll 8
    for (int d = 0; d < 32; ++d) {
        a += hsum4(wq4[d]);
        c += hsum4(wk4[d]);
        e += hsum4(wv4[d]);
    }
    float dac = a * c;         // -> alpha after reduce
    float dcq = c * bq[k];     // -> gamma after reduce
    float sbv = bv[k];
    #pragma unroll
    for (int off = 32; off > 0; off >>= 1) {
        dac += __shfl_down(dac, off, 64);
        dcq += __shfl_down(dcq, off, 64);
        e   += __shfl_down(e,   off, 64);
        sbv += __shfl_down(sbv, off, 64);
    }
    if (k == 0) {
        sc[0] = dac * 0.125f;          // alpha
        sc[1] = dcq * 0.125f;          // gamma
        sc[2] = e   * (1.0f / 64.0f);  // Ebar
        sc[3] = sbv * (1.0f / 64.0f);  // bvbar
    }
}

// One block per (b,n,i): 256 threads, thread = s.
__global__ __launch_bounds__(256) void mm_attn(const float* __restrict__ x,
                                               const float* __restrict__ sc,
                                               float* __restrict__ out) {
    __shared__ float xs[4][256];
    const int bni = blockIdx.x;          // ((b*51+n)*4 + i)
    const int i   = bni & 3;
    const int tid = threadIdx.x;
    const float* xb = x + (size_t)(bni >> 2) * 1024;
    #pragma unroll
    for (int r = 0; r < 4; ++r) xs[r][tid] = xb[r * 256 + tid];
    __syncthreads();

    const float alpha = sc[0], gamma = sc[1], Ebar = sc[2], bvbar = sc[3];
    // fold log2(e): weights are 2^(c2 * x_t)
    const float c2 = (alpha * xs[i][tid] + gamma) * 1.4426950408889634f;

    float acc = 0.f;
    #pragma unroll
    for (int jj = 1; jj < 4; ++jj) {
        const int j = (i + jj) & 3;                 // uniform across the block
        const float4* xj = reinterpret_cast<const float4*>(xs[j]);
        float n0 = 0.f, n1 = 0.f, n2 = 0.f, n3 = 0.f, d0 = 0.f, d1 = 0.f;
        #pragma unroll 4
        for (int t = 0; t < 64; ++t) {              // 256 elements as float4
            float4 v = xj[t];                       // wave-uniform LDS broadcast
            // dual-pipe: .x/.z on HW trans pipe, .y/.w on VALU poly
            float w0 = EXP2(c2 * v.x);
            float w1 = exp2_poly(c2 * v.y);
            float w2 = EXP2(c2 * v.z);
            float w3 = exp2_poly(c2 * v.w);
            n0 = fmaf(w0, v.x, n0);
            n1 = fmaf(w1, v.y, n1);
            n2 = fmaf(w2, v.z, n2);
            n3 = fmaf(w3, v.w, n3);
            d0 += w0 + w2;
            d1 += w1 + w3;
        }
        acc += ((n0 + n1) + (n2 + n3)) / (d0 + d1);
    }
    out[(size_t)bni * 256 + tid] = fmaf(Ebar * (1.0f / 3.0f), acc, bvbar);
}

extern "C" void kernel_launch(void* const* d_in, const int* in_sizes, int n_in,
                              void* d_out, int out_size, void* d_ws, size_t ws_size,
                              hipStream_t stream) {
    const float* x  = (const float*)d_in[0];
    const float* Wq = (const float*)d_in[1];
    const float* bq = (const float*)d_in[2];
    const float* Wk = (const float*)d_in[3];
    const float* bk = (const float*)d_in[4];
    const float* Wv = (const float*)d_in[5];
    const float* bv = (const float*)d_in[6];
    float* out = (float*)d_out;
    float* sc  = (float*)d_ws;   // 4 floats of scratch

    mm_prep<<<1, 64, 0, stream>>>(Wq, bq, Wk, bk, Wv, bv, sc);
    mm_attn<<<816, 256, 0, stream>>>(x, sc, out);
}

// Round 16
// 98.061 us; speedup vs baseline: 1.1507x; 1.1507x over previous
//
#include <hip/hip_runtime.h>

// MultiModalFusion collapses analytically (exact, softmax shift-invariance):
//   attn = softmax_t(c_s * x_j[t]),  c_s = alpha*x_i[s] + gamma
//   out[b,n,i,s] = Ebar * mean_{j!=i} [ (sum_t e^{c x_jt} x_jt)/(sum_t e^{c x_jt}) ] + bvbar
//
// Round-12 postmortem: dual-pipe poly exp REGRESSED (47.0 vs 45.7 us, VALUBusy
// 41->67% with flat time) -> no pipe is saturated; waves issue only ~21% of
// resident cycles -> dependency-latency bound at 3.2 waves/SIMD, and the grid
// (816x4 waves = 40% of wave slots) caps occupancy. This version: all-HW exp,
// 1024-thread blocks, 4-way t-split + LDS combine -> 2 resident blocks/CU =
// 32 waves/CU (max), per-wave work quartered.

#if __has_builtin(__builtin_amdgcn_exp2f)
#define EXP2(v) __builtin_amdgcn_exp2f(v)
#else
#define EXP2(v) exp2f(v)
#endif

static __device__ __forceinline__ float hsum4(float4 v) { return (v.x + v.y) + (v.z + v.w); }

// One wave: compute the 4 scalars into sc[0..3].
__global__ void mm_prep(const float* __restrict__ Wq, const float* __restrict__ bq,
                        const float* __restrict__ Wk, const float* __restrict__ bk,
                        const float* __restrict__ Wv, const float* __restrict__ bv,
                        float* __restrict__ sc) {
    const int k = threadIdx.x;  // 0..63
    const float4* wq4 = reinterpret_cast<const float4*>(Wq) + k * 32;
    const float4* wk4 = reinterpret_cast<const float4*>(Wk) + k * 32;
    const float4* wv4 = reinterpret_cast<const float4*>(Wv) + k * 32;
    float a = 0.f, c = 0.f, e = 0.f;
    #pragma unroll 8
    for (int d = 0; d < 32; ++d) {
        a += hsum4(wq4[d]);
        c += hsum4(wk4[d]);
        e += hsum4(wv4[d]);
    }
    float dac = a * c;         // -> alpha after reduce
    float dcq = c * bq[k];     // -> gamma after reduce
    float sbv = bv[k];
    #pragma unroll
    for (int off = 32; off > 0; off >>= 1) {
        dac += __shfl_down(dac, off, 64);
        dcq += __shfl_down(dcq, off, 64);
        e   += __shfl_down(e,   off, 64);
        sbv += __shfl_down(sbv, off, 64);
    }
    if (k == 0) {
        sc[0] = dac * 0.125f;          // alpha
        sc[1] = dcq * 0.125f;          // gamma
        sc[2] = e   * (1.0f / 64.0f);  // Ebar
        sc[3] = sbv * (1.0f / 64.0f);  // bvbar
    }
}

// One block per (b,n,i): 1024 threads = (h, s); h = quarter of the t-range.
__global__ __launch_bounds__(1024) void mm_attn(const float* __restrict__ x,
                                                const float* __restrict__ sc,
                                                float* __restrict__ out) {
    __shared__ float xs[4][256];
    __shared__ float pn[4][3][256];   // partial numerators  [quarter][jj][s]
    __shared__ float pd[4][3][256];   // partial denominators
    const int bni = blockIdx.x;       // ((b*51+n)*4 + i)
    const int i   = bni & 3;
    const int tid = threadIdx.x;      // 0..1023
    const int s   = tid & 255;
    const int h   = tid >> 8;         // 0..3
    const float* xb = x + (size_t)(bni >> 2) * 1024;
    xs[h][s] = xb[h * 256 + s];       // 1024 threads load 1024 floats
    __syncthreads();

    const float alpha = sc[0], gamma = sc[1], Ebar = sc[2], bvbar = sc[3];
    // fold log2(e): weights are 2^(c2 * x_t)
    const float c2 = (alpha * xs[i][s] + gamma) * 1.4426950408889634f;

    #pragma unroll
    for (int jj = 1; jj < 4; ++jj) {
        const int j = (i + jj) & 3;                       // uniform across block
        const float4* xj = reinterpret_cast<const float4*>(xs[j]) + h * 16;
        float n0 = 0.f, n1 = 0.f, n2 = 0.f, n3 = 0.f, d0 = 0.f, d1 = 0.f;
        #pragma unroll
        for (int t = 0; t < 16; ++t) {                    // 64 elems as float4
            float4 v = xj[t];                             // wave-uniform LDS broadcast
            float w0 = EXP2(c2 * v.x);
            float w1 = EXP2(c2 * v.y);
            float w2 = EXP2(c2 * v.z);
            float w3 = EXP2(c2 * v.w);
            n0 = fmaf(w0, v.x, n0);
            n1 = fmaf(w1, v.y, n1);
            n2 = fmaf(w2, v.z, n2);
            n3 = fmaf(w3, v.w, n3);
            d0 += w0 + w2;
            d1 += w1 + w3;
        }
        pn[h][jj - 1][s] = (n0 + n1) + (n2 + n3);
        pd[h][jj - 1][s] = d0 + d1;
    }
    __syncthreads();

    if (tid < 256) {
        float acc = 0.f;
        #pragma unroll
        for (int jj = 0; jj < 3; ++jj) {
            float nsum = (pn[0][jj][tid] + pn[1][jj][tid]) + (pn[2][jj][tid] + pn[3][jj][tid]);
            float dsum = (pd[0][jj][tid] + pd[1][jj][tid]) + (pd[2][jj][tid] + pd[3][jj][tid]);
            acc += nsum / dsum;
        }
        out[(size_t)bni * 256 + tid] = fmaf(Ebar * (1.0f / 3.0f), acc, bvbar);
    }
}

extern "C" void kernel_launch(void* const* d_in, const int* in_sizes, int n_in,
                              void* d_out, int out_size, void* d_ws, size_t ws_size,
                              hipStream_t stream) {
    const float* x  = (const float*)d_in[0];
    const float* Wq = (const float*)d_in[1];
    const float* bq = (const float*)d_in[2];
    const float* Wk = (const float*)d_in[3];
    const float* bk = (const float*)d_in[4];
    const float* Wv = (const float*)d_in[5];
    const float* bv = (const float*)d_in[6];
    float* out = (float*)d_out;
    float* sc  = (float*)d_ws;   // 4 floats of scratch

    mm_prep<<<1, 64, 0, stream>>>(Wq, bq, Wk, bk, Wv, bv, sc);
    mm_attn<<<816, 1024, 0, stream>>>(x, sc, out);
}